// Round 1
// baseline (910.365 us; speedup 1.0000x reference)
//
#include <hip/hip_runtime.h>
#include <hip/hip_bf16.h>

#define NN 100000
#define NE 1600000
#define D_IN 7
#define H1 64
#define H2 32
#define NG 64

// ---------------- degree histogram ----------------
__global__ void k_deg(const int* __restrict__ dst, float* __restrict__ deg) {
    int e = blockIdx.x * 256 + threadIdx.x;
    if (e < NE) atomicAdd(&deg[dst[e]], 1.0f);
}

// dis = rsqrt(deg + 1), in place over deg
__global__ void k_dis(float* __restrict__ deg) {
    int i = blockIdx.x * 256 + threadIdx.x;
    if (i < NN) deg[i] = rsqrtf(deg[i] + 1.0f);
}

// ---------------- mean pool over sorted batch ----------------
__device__ int lower_bound_i(const int* a, int n, int v) {
    int lo = 0, hi = n;
    while (lo < hi) { int mid = (lo + hi) >> 1; if (a[mid] < v) lo = mid + 1; else hi = mid; }
    return lo;
}

__global__ void k_pool(const float* __restrict__ x, const int* __restrict__ batch,
                       float* __restrict__ outp) {
    __shared__ int bounds[2];
    __shared__ float red[256 * D_IN];
    int g = blockIdx.x, t = threadIdx.x;
    if (t == 0) {
        bounds[0] = lower_bound_i(batch, NN, g);
        bounds[1] = lower_bound_i(batch, NN, g + 1);
    }
    __syncthreads();
    int s = bounds[0], e = bounds[1];
    float acc[D_IN];
#pragma unroll
    for (int k = 0; k < D_IN; k++) acc[k] = 0.f;
    for (int n = s + t; n < e; n += 256) {
#pragma unroll
        for (int k = 0; k < D_IN; k++) acc[k] += x[n * D_IN + k];
    }
#pragma unroll
    for (int k = 0; k < D_IN; k++) red[t * D_IN + k] = acc[k];
    __syncthreads();
    if (t < D_IN) {
        float sum = 0.f;
        for (int i = 0; i < 256; i++) sum += red[i * D_IN + t];
        float cnt = (float)(e - s);
        outp[g * D_IN + t] = sum / fmaxf(cnt, 1.f);
    }
}

// ---------------- xw1 = x @ W1 ; agg1 = dis^2 * xw1 (self-loop init) ----------------
__global__ void k_mm1(const float* __restrict__ x, const float* __restrict__ W1,
                      const float* __restrict__ dis,
                      float* __restrict__ xw1, float* __restrict__ agg1) {
    __shared__ float sW[D_IN * H1];
    int t = threadIdx.x;
    for (int i = t; i < D_IN * H1; i += 256) sW[i] = W1[i];
    __syncthreads();
    int idx = blockIdx.x * 256 + t;
    if (idx < NN * H1) {
        int n = idx >> 6, h = idx & 63;
        float a = 0.f;
#pragma unroll
        for (int k = 0; k < D_IN; k++) a += x[n * D_IN + k] * sW[k * H1 + h];
        xw1[idx] = a;
        float d = dis[n];
        agg1[idx] = d * d * a;
    }
}

// ---------------- edge scatter layer 1 (64 ch) ----------------
__global__ void k_edge1(const int* __restrict__ src, const int* __restrict__ dst,
                        const float* __restrict__ dis, const float* __restrict__ xw1,
                        float* __restrict__ agg1) {
    int idx = blockIdx.x * 256 + threadIdx.x;
    if (idx >= NE * 64) return;
    int e = idx >> 6, ch = idx & 63;
    int s = src[e], d = dst[e];
    float w = dis[s] * dis[d];
    atomicAdd(&agg1[d * 64 + ch], w * xw1[s * 64 + ch]);
}

// ---------------- h1 = relu(agg1+b1); xw2/xw3 = h1@W2/W3; init agg2/agg3 ----------------
__global__ void k_mm2(const float* __restrict__ agg1, const float* __restrict__ b1,
                      const float* __restrict__ W2, const float* __restrict__ W3,
                      const float* __restrict__ dis,
                      float* __restrict__ xw2, float* __restrict__ xw3,
                      float* __restrict__ agg2, float* __restrict__ agg3) {
    __shared__ float sW2[H1 * H2];
    __shared__ float sW3[H1 * H2];
    __shared__ float sb1[H1];
    __shared__ float sh[8 * H1];
    int t = threadIdx.x;
    for (int i = t; i < H1 * H2; i += 256) { sW2[i] = W2[i]; sW3[i] = W3[i]; }
    if (t < H1) sb1[t] = b1[t];
    __syncthreads();
    int base_n = blockIdx.x * 8;
    for (int i = t; i < 8 * H1; i += 256) {
        int n = base_n + (i >> 6);
        sh[i] = (n < NN) ? fmaxf(agg1[n * H1 + (i & 63)] + sb1[i & 63], 0.f) : 0.f;
    }
    __syncthreads();
    int n = base_n + (t >> 5), h = t & 31;
    if (n < NN) {
        float a2 = 0.f, a3 = 0.f;
        const float* hr = &sh[(t >> 5) * H1];
#pragma unroll
        for (int k = 0; k < H1; k++) {
            float hv = hr[k];
            a2 += hv * sW2[k * H2 + h];
            a3 += hv * sW3[k * H2 + h];
        }
        float d = dis[n], d2 = d * d;
        int o = n * H2 + h;
        xw2[o] = a2; xw3[o] = a3;
        agg2[o] = d2 * a2; agg3[o] = d2 * a3;
    }
}

// ---------------- edge scatter layer 2 (32 ch, both matrices) ----------------
__global__ void k_edge2(const int* __restrict__ src, const int* __restrict__ dst,
                        const float* __restrict__ dis,
                        const float* __restrict__ xw2, const float* __restrict__ xw3,
                        float* __restrict__ agg2, float* __restrict__ agg3) {
    int idx = blockIdx.x * 256 + threadIdx.x;
    if (idx >= NE * 32) return;
    int e = idx >> 5, ch = idx & 31;
    int s = src[e], d = dst[e];
    float w = dis[s] * dis[d];
    int so = s * H2 + ch, dofs = d * H2 + ch;
    atomicAdd(&agg2[dofs], w * xw2[so]);
    atomicAdd(&agg3[dofs], w * xw3[so]);
}

// ---------------- epilogue: mu/logvar relu+bias in place, z = eps*exp(lv)+mu ----------------
__global__ void k_final(const float* __restrict__ b2, const float* __restrict__ b3,
                        const float* __restrict__ eps,
                        float* __restrict__ z, float* __restrict__ mu_io,
                        float* __restrict__ lv_io) {
    int c = blockIdx.x * 256 + threadIdx.x;
    if (c < NN * H2) {
        int ch = c & 31;
        float m = fmaxf(mu_io[c] + b2[ch], 0.f);
        float l = fmaxf(lv_io[c] + b3[ch], 0.f);
        mu_io[c] = m;
        lv_io[c] = l;
        z[c] = eps[c] * expf(l) + m;
    }
}

extern "C" void kernel_launch(void* const* d_in, const int* in_sizes, int n_in,
                              void* d_out, int out_size, void* d_ws, size_t ws_size,
                              hipStream_t stream) {
    const float* x   = (const float*)d_in[0];
    const int*   ei  = (const int*)d_in[1];   // [2, E] -> src = ei, dst = ei+NE
    const int*   bat = (const int*)d_in[2];
    const float* W1  = (const float*)d_in[3];
    const float* b1  = (const float*)d_in[4];
    const float* W2  = (const float*)d_in[5];
    const float* b2  = (const float*)d_in[6];
    const float* W3  = (const float*)d_in[7];
    const float* b3  = (const float*)d_in[8];
    const float* eps = (const float*)d_in[9];

    const int* src = ei;
    const int* dst = ei + NE;

    float* out = (float*)d_out;
    float* out_z    = out;                               // [N,32]
    float* out_pool = out + (size_t)NN * H2;             // [G,7]
    float* out_mu   = out_pool + NG * D_IN;              // [N,32]
    float* out_lv   = out_mu + (size_t)NN * H2;          // [N,32]

    // workspace layout (floats)
    float* ws   = (float*)d_ws;
    float* dis  = ws;                         // N
    float* xw1  = dis + NN;                   // N*64
    float* agg1 = xw1 + (size_t)NN * H1;      // N*64
    float* xw2  = agg1 + (size_t)NN * H1;     // N*32
    float* xw3  = xw2 + (size_t)NN * H2;      // N*32

    // zero degree accumulator only (everything else is plain-stored before use)
    hipMemsetAsync(dis, 0, NN * sizeof(float), stream);

    k_deg<<<(NE + 255) / 256, 256, 0, stream>>>(dst, dis);
    k_dis<<<(NN + 255) / 256, 256, 0, stream>>>(dis);

    k_pool<<<NG, 256, 0, stream>>>(x, bat, out_pool);

    k_mm1<<<(NN * H1 + 255) / 256, 256, 0, stream>>>(x, W1, dis, xw1, agg1);

    k_edge1<<<(NE * 64 + 255) / 256, 256, 0, stream>>>(src, dst, dis, xw1, agg1);

    k_mm2<<<(NN + 7) / 8, 256, 0, stream>>>(agg1, b1, W2, W3, dis, xw2, xw3, out_mu, out_lv);

    k_edge2<<<(NE * 32 + 255) / 256, 256, 0, stream>>>(src, dst, dis, xw2, xw3, out_mu, out_lv);

    k_final<<<(NN * H2 + 255) / 256, 256, 0, stream>>>(b2, b3, eps, out_z, out_mu, out_lv);
}

// Round 2
// 625.807 us; speedup vs baseline: 1.4547x; 1.4547x over previous
//
#include <hip/hip_runtime.h>
#include <hip/hip_bf16.h>

#define NN 100000
#define NE 1600000
#define D_IN 7
#define H1 64
#define H2 32
#define NG 64
#define NB 391   // (NN+255)/256

// ---------------- in-degree histogram (int) ----------------
__global__ void k_hist(const int* __restrict__ dst, int* __restrict__ cnt) {
    int e = blockIdx.x * 256 + threadIdx.x;
    if (e < NE) atomicAdd(&cnt[dst[e]], 1);
}

// ---------------- scan stage 1: per-block sums of cnt ----------------
__global__ void k_scan1(const int* __restrict__ cnt, int* __restrict__ partials) {
    __shared__ int red[256];
    int t = threadIdx.x;
    int i = blockIdx.x * 256 + t;
    red[t] = (i < NN) ? cnt[i] : 0;
    __syncthreads();
    for (int off = 128; off > 0; off >>= 1) {
        if (t < off) red[t] += red[t + off];
        __syncthreads();
    }
    if (t == 0) partials[blockIdx.x] = red[0];
}

// ---------------- scan stage 2: exclusive scan of 391 partials (1 block) ----------------
__global__ void k_scan2(int* __restrict__ partials) {
    __shared__ int s[512];
    int t = threadIdx.x;
    int val = (t < NB) ? partials[t] : 0;
    s[t] = val;
    __syncthreads();
    for (int off = 1; off < 512; off <<= 1) {
        int add = (t >= off) ? s[t - off] : 0;
        __syncthreads();
        s[t] += add;
        __syncthreads();
    }
    if (t < NB) partials[t] = s[t] - val;  // exclusive
}

// ---------------- scan stage 3: row_start, cursor, dis ----------------
__global__ void k_scan3(const int* __restrict__ cnt, const int* __restrict__ partials,
                        int* __restrict__ row_start, int* __restrict__ cursor,
                        float* __restrict__ dis) {
    __shared__ int s[256];
    int t = threadIdx.x;
    int i = blockIdx.x * 256 + t;
    int val = (i < NN) ? cnt[i] : 0;
    s[t] = val;
    __syncthreads();
    for (int off = 1; off < 256; off <<= 1) {
        int add = (t >= off) ? s[t - off] : 0;
        __syncthreads();
        s[t] += add;
        __syncthreads();
    }
    if (i < NN) {
        int start = partials[blockIdx.x] + s[t] - val;
        row_start[i] = start;
        cursor[i] = start;
        dis[i] = rsqrtf((float)val + 1.0f);
    }
}

// ---------------- CSR fill: store (src, w) packed per edge ----------------
__global__ void k_fill(const int* __restrict__ src, const int* __restrict__ dst,
                       const float* __restrict__ dis,
                       int* __restrict__ cursor, float2* __restrict__ csr_sw) {
    int e = blockIdx.x * 256 + threadIdx.x;
    if (e >= NE) return;
    int s = src[e], d = dst[e];
    int pos = atomicAdd(&cursor[d], 1);
    float w = dis[s] * dis[d];
    csr_sw[pos] = make_float2(__int_as_float(s), w);
}

// ---------------- mean pool over sorted batch ----------------
__device__ int lower_bound_i(const int* a, int n, int v) {
    int lo = 0, hi = n;
    while (lo < hi) { int mid = (lo + hi) >> 1; if (a[mid] < v) lo = mid + 1; else hi = mid; }
    return lo;
}

__global__ void k_pool(const float* __restrict__ x, const int* __restrict__ batch,
                       float* __restrict__ outp) {
    __shared__ int bounds[2];
    __shared__ float red[256 * D_IN];
    int g = blockIdx.x, t = threadIdx.x;
    if (t == 0) {
        bounds[0] = lower_bound_i(batch, NN, g);
        bounds[1] = lower_bound_i(batch, NN, g + 1);
    }
    __syncthreads();
    int s = bounds[0], e = bounds[1];
    float acc[D_IN];
#pragma unroll
    for (int k = 0; k < D_IN; k++) acc[k] = 0.f;
    for (int n = s + t; n < e; n += 256) {
#pragma unroll
        for (int k = 0; k < D_IN; k++) acc[k] += x[n * D_IN + k];
    }
#pragma unroll
    for (int k = 0; k < D_IN; k++) red[t * D_IN + k] = acc[k];
    __syncthreads();
    if (t < D_IN) {
        float sum = 0.f;
        for (int i = 0; i < 256; i++) sum += red[i * D_IN + t];
        float cnt = (float)(e - s);
        outp[g * D_IN + t] = sum / fmaxf(cnt, 1.f);
    }
}

// ---------------- xw1 = x @ W1 ----------------
__global__ void k_mm1(const float* __restrict__ x, const float* __restrict__ W1,
                      float* __restrict__ xw1) {
    __shared__ float sW[D_IN * H1];
    int t = threadIdx.x;
    for (int i = t; i < D_IN * H1; i += 256) sW[i] = W1[i];
    __syncthreads();
    int idx = blockIdx.x * 256 + t;
    if (idx < NN * H1) {
        int n = idx >> 6, h = idx & 63;
        float a = 0.f;
#pragma unroll
        for (int k = 0; k < D_IN; k++) a += x[n * D_IN + k] * sW[k * H1 + h];
        xw1[idx] = a;
    }
}

// ---------------- layer-1 aggregation: one wave per node, gather over CSR ----------------
__global__ __launch_bounds__(256) void k_agg1(const int* __restrict__ row_start,
                                              const int* __restrict__ cnt,
                                              const float* __restrict__ dis,
                                              const float2* __restrict__ csr_sw,
                                              const float* __restrict__ xw1,
                                              float* __restrict__ agg1) {
    int node = (blockIdx.x * 256 + threadIdx.x) >> 6;
    int lane = threadIdx.x & 63;
    if (node >= NN) return;
    int start = row_start[node];
    int c = cnt[node];
    float dn = dis[node];
    float acc = dn * dn * xw1[node * H1 + lane];  // self-loop
    for (int j = 0; j < c; j++) {
        float2 sw = csr_sw[start + j];       // broadcast 8B load
        int s = __float_as_int(sw.x);
        acc += sw.y * xw1[s * H1 + lane];    // 256B coalesced gather
    }
    agg1[node * H1 + lane] = acc;
}

// ---------------- h1 = relu(agg1+b1); xw2 = h1@W2; xw3 = h1@W3 ----------------
__global__ void k_mm2(const float* __restrict__ agg1, const float* __restrict__ b1,
                      const float* __restrict__ W2, const float* __restrict__ W3,
                      float* __restrict__ xw2, float* __restrict__ xw3) {
    __shared__ float sW2[H1 * H2];
    __shared__ float sW3[H1 * H2];
    __shared__ float sb1[H1];
    __shared__ float sh[8 * H1];
    int t = threadIdx.x;
    for (int i = t; i < H1 * H2; i += 256) { sW2[i] = W2[i]; sW3[i] = W3[i]; }
    if (t < H1) sb1[t] = b1[t];
    __syncthreads();
    int base_n = blockIdx.x * 8;
    for (int i = t; i < 8 * H1; i += 256) {
        int n = base_n + (i >> 6);
        sh[i] = (n < NN) ? fmaxf(agg1[n * H1 + (i & 63)] + sb1[i & 63], 0.f) : 0.f;
    }
    __syncthreads();
    int n = base_n + (t >> 5), h = t & 31;
    if (n < NN) {
        float a2 = 0.f, a3 = 0.f;
        const float* hr = &sh[(t >> 5) * H1];
#pragma unroll
        for (int k = 0; k < H1; k++) {
            float hv = hr[k];
            a2 += hv * sW2[k * H2 + h];
            a3 += hv * sW3[k * H2 + h];
        }
        int o = n * H2 + h;
        xw2[o] = a2; xw3[o] = a3;
    }
}

// ---------------- layer-2 aggregation (both mats) + fused epilogue ----------------
// wave per node; lanes 0-31: mu path (xw2), lanes 32-63: logvar path (xw3)
__global__ __launch_bounds__(256) void k_agg2(const int* __restrict__ row_start,
                                              const int* __restrict__ cnt,
                                              const float* __restrict__ dis,
                                              const float2* __restrict__ csr_sw,
                                              const float* __restrict__ xw2,
                                              const float* __restrict__ xw3,
                                              const float* __restrict__ b2,
                                              const float* __restrict__ b3,
                                              const float* __restrict__ eps,
                                              float* __restrict__ out_z,
                                              float* __restrict__ out_mu,
                                              float* __restrict__ out_lv) {
    int node = (blockIdx.x * 256 + threadIdx.x) >> 6;
    int lane = threadIdx.x & 63;
    if (node >= NN) return;
    int ch = lane & 31;
    bool is_mu = lane < 32;
    const float* xw = is_mu ? xw2 : xw3;
    int start = row_start[node];
    int c = cnt[node];
    float dn = dis[node];
    float acc = dn * dn * xw[node * H2 + ch];  // self-loop
    for (int j = 0; j < c; j++) {
        float2 sw = csr_sw[start + j];
        int s = __float_as_int(sw.x);
        acc += sw.y * xw[s * H2 + ch];
    }
    float bias = is_mu ? b2[ch] : b3[ch];
    float val = fmaxf(acc + bias, 0.f);       // relu(agg + b)
    float other = __shfl(val, lane ^ 32, 64); // partner value
    int o = node * H2 + ch;
    if (is_mu) {
        out_mu[o] = val;
        out_z[o] = eps[o] * __expf(other) + val;  // other = logvar
    } else {
        out_lv[o] = val;
    }
}

extern "C" void kernel_launch(void* const* d_in, const int* in_sizes, int n_in,
                              void* d_out, int out_size, void* d_ws, size_t ws_size,
                              hipStream_t stream) {
    const float* x   = (const float*)d_in[0];
    const int*   ei  = (const int*)d_in[1];   // [2, E]
    const int*   bat = (const int*)d_in[2];
    const float* W1  = (const float*)d_in[3];
    const float* b1  = (const float*)d_in[4];
    const float* W2  = (const float*)d_in[5];
    const float* b2  = (const float*)d_in[6];
    const float* W3  = (const float*)d_in[7];
    const float* b3  = (const float*)d_in[8];
    const float* eps = (const float*)d_in[9];

    const int* src = ei;
    const int* dst = ei + NE;

    float* out = (float*)d_out;
    float* out_z    = out;                               // [N,32]
    float* out_pool = out + (size_t)NN * H2;             // [G,7]
    float* out_mu   = out_pool + NG * D_IN;              // [N,32]
    float* out_lv   = out_mu + (size_t)NN * H2;          // [N,32]

    // workspace layout (4-byte words); xw1 offset kept 256B-aligned
    int*    cnt       = (int*)d_ws;                      // N
    int*    row_start = cnt + NN;                        // N
    int*    cursor    = row_start + NN;                  // N
    int*    partials  = cursor + NN;                     // 512
    float*  dis       = (float*)(partials + 512);        // N
    float2* csr_sw    = (float2*)(dis + NN);             // E float2 (8B each)
    float*  xw1       = (float*)(csr_sw + NE);           // N*64
    float*  agg1      = xw1 + (size_t)NN * H1;           // N*64
    float*  xw2       = xw1;                             // alias: xw1 dead after k_agg1
    float*  xw3       = xw1 + (size_t)NN * H2;

    hipMemsetAsync(cnt, 0, NN * sizeof(int), stream);

    k_hist <<<(NE + 255) / 256, 256, 0, stream>>>(dst, cnt);
    k_scan1<<<NB, 256, 0, stream>>>(cnt, partials);
    k_scan2<<<1, 512, 0, stream>>>(partials);
    k_scan3<<<NB, 256, 0, stream>>>(cnt, partials, row_start, cursor, dis);
    k_fill <<<(NE + 255) / 256, 256, 0, stream>>>(src, dst, dis, cursor, csr_sw);

    k_pool <<<NG, 256, 0, stream>>>(x, bat, out_pool);

    k_mm1  <<<(NN * H1 + 255) / 256, 256, 0, stream>>>(x, W1, xw1);
    k_agg1 <<<(NN * 64 + 255) / 256, 256, 0, stream>>>(row_start, cnt, dis, csr_sw, xw1, agg1);
    k_mm2  <<<(NN + 7) / 8, 256, 0, stream>>>(agg1, b1, W2, W3, xw2, xw3);
    k_agg2 <<<(NN * 64 + 255) / 256, 256, 0, stream>>>(row_start, cnt, dis, csr_sw, xw2, xw3,
                                                       b2, b3, eps, out_z, out_mu, out_lv);
}